// Round 10
// baseline (275.284 us; speedup 1.0000x reference)
//
#include <hip/hip_runtime.h>

#define IMG_H 512
#define IMG_W 512
#define BATCH 32
#define TW 256              // block column span (1 col/thread)
#define TH 16               // output rows per block
#define NBLK (2 * 32 * 32)  // 2048 blocks

// ---- staging: global -> regs (issue), regs -> LDS (consume) --------------
// All indices literal after unroll; N is a macro literal so `i<N` folds.
#define STAGE(C0, N)                                                          \
  _Pragma("unroll") for (int i = 0; i < 7; ++i) {                             \
    if (i < (N)) {                                                            \
      const int gy = y0 - 3 + (C0) + i;                                       \
      pxa[i] = pya[i] = pxb[i] = pyb[i] = 0.f;                                \
      if ((unsigned)gy < (unsigned)IMG_H) { /* wave-uniform */                \
        const float* xrow = Xb + (size_t)gy * IMG_W;                          \
        const float* yrow = Yb + (size_t)gy * IMG_W;                          \
        if (ok1) { pxa[i] = xrow[g1]; pya[i] = yrow[g1]; }                    \
        if (ok2) { pxb[i] = xrow[g2]; pyb[i] = yrow[g2]; }                    \
      }                                                                       \
    }                                                                         \
  }

#define STORE(BUF, N)                                                         \
  _Pragma("unroll") for (int i = 0; i < 7; ++i) {                             \
    if (i < (N)) {                                                            \
      sbuf[BUF][i * 264 + t] = make_float2(pxa[i], pya[i]);                   \
      if (t < 6) sbuf[BUF][i * 264 + 256 + t] = make_float2(pxb[i], pyb[i]);  \
    }                                                                         \
  }

// ---- one input row: h-pass from LDS, vertical ring scatter, emit ---------
// R = absolute tile row (literal), RR = row within chunk, BUF = LDS buffer.
#define ROW_BODY(R, RR, BUF)                                                  \
  {                                                                           \
    float hx = 0.f, hy = 0.f, hxx = 0.f, hyy = 0.f, hxy = 0.f;                \
    _Pragma("unroll") for (int k = 0; k < 7; ++k) {                           \
      const float2 p = sbuf[BUF][(RR)*264 + t + k];                           \
      const float wx = w[k] * p.x;                                            \
      const float wy = w[k] * p.y;                                            \
      hx = fmaf(w[k], p.x, hx);                                               \
      hy = fmaf(w[k], p.y, hy);                                               \
      hxx = fmaf(wx, p.x, hxx);                                               \
      hyy = fmaf(wy, p.y, hyy);                                               \
      hxy = fmaf(wx, p.y, hxy);                                               \
    }                                                                         \
    _Pragma("unroll") for (int tt = 0; tt < 7; ++tt) {                        \
      const int o = (R)-tt;                                                   \
      if (o >= 0 && o < TH) {                                                 \
        const int slot = o % 7;                                               \
        const float wt = w[tt];                                               \
        acc[slot][0] = fmaf(wt, hx, acc[slot][0]);                            \
        acc[slot][1] = fmaf(wt, hy, acc[slot][1]);                            \
        acc[slot][2] = fmaf(wt, hxx, acc[slot][2]);                           \
        acc[slot][3] = fmaf(wt, hyy, acc[slot][3]);                           \
        acc[slot][4] = fmaf(wt, hxy, acc[slot][4]);                           \
      }                                                                       \
    }                                                                         \
    if ((R) >= 6 && (R)-6 < TH) {                                             \
      const int slot = ((R)-6) % 7;                                           \
      const float mu_x = acc[slot][0];                                        \
      const float mu_y = acc[slot][1];                                        \
      const float mx2 = mu_x * mu_x;                                          \
      const float my2 = mu_y * mu_y;                                          \
      const float mxy = mu_x * mu_y;                                          \
      const float sxx = acc[slot][2] - mx2;                                   \
      const float syy = acc[slot][3] - my2;                                   \
      const float sxy = acc[slot][4] - mxy;                                   \
      const float num = (2.f * mxy + 1e-4f) * (2.f * sxy + 9e-4f);            \
      const float den = (mx2 + my2 + 1e-4f) * (sxx + syy + 9e-4f);            \
      tsum += num * __builtin_amdgcn_rcpf(den);                               \
      acc[slot][0] = acc[slot][1] = acc[slot][2] = acc[slot][3] =             \
          acc[slot][4] = 0.f;                                                 \
    }                                                                         \
  }

// Chunked pipeline: loads for chunk k+1 are issued right AFTER a barrier and
// consumed (ds_write) after ~1500 cycles of chunk-k compute, so the
// compiler's mandatory vmcnt(0) drain at the next s_barrier is already
// satisfied. 4 barriers per block instead of 22.  NO min-occupancy
// launch_bounds: the 28-register prefetch needs allocator headroom (R3's
// regression was (256,4) forcing 64 VGPRs -> 209 MB scratch spill).
__global__ __launch_bounds__(256) void ssim_main(
    const float* __restrict__ X, const float* __restrict__ Y,
    const float* __restrict__ K, float* __restrict__ partials) {
  __shared__ float2 sbuf[2][7 * 264];   // 29568 B, double-buffered chunks
  __shared__ float wsum[4];

  const int t = threadIdx.x;
  const int x0 = blockIdx.x * TW;
  const int y0 = blockIdx.y * TH;
  const size_t img = (size_t)IMG_H * IMG_W;
  const float* Xb = X + blockIdx.z * img;
  const float* Yb = Y + blockIdx.z * img;

  // Exact separable 1D weights from center row of the provided 7x7 kernel:
  // k[3][j] = w3*w_j, sum_j w_j = 1  =>  w_j = k[3][j] / sum_j k[3][j].
  float w[7];
  {
    float rs = 0.f;
#pragma unroll
    for (int j = 0; j < 7; ++j) { w[j] = K[3 * 7 + j]; rs += w[j]; }
    const float inv = 1.f / rs;
#pragma unroll
    for (int j = 0; j < 7; ++j) w[j] *= inv;
  }

  // Loop-invariant horizontal addressing (LDS slot s = image col x0-3+s).
  const int g1 = x0 - 3 + t;
  const bool ok1 = (unsigned)g1 < (unsigned)IMG_W;
  const int g2 = g1 + TW;
  const bool ok2 = (t < 6) && ((unsigned)g2 < (unsigned)IMG_W);

  float acc[7][5];
#pragma unroll
  for (int s = 0; s < 7; ++s)
#pragma unroll
    for (int c = 0; c < 5; ++c) acc[s][c] = 0.f;
  float tsum = 0.f;

  float pxa[7], pya[7], pxb[7], pyb[7];   // chunk prefetch (static indices)

  // chunk 0: rows 0-6
  STAGE(0, 7);
  STORE(0, 7);
  __syncthreads();
  STAGE(7, 7);                           // issue chunk1 loads NOW
#pragma unroll
  for (int rr = 0; rr < 7; ++rr) ROW_BODY(rr, rr, 0);      // ~1500 cyc cover
  STORE(1, 7);                           // vmcnt wait ~satisfied here
  __syncthreads();                       // lgkm-only drain
  STAGE(14, 7);                          // issue chunk2 loads
#pragma unroll
  for (int rr = 0; rr < 7; ++rr) ROW_BODY(7 + rr, rr, 1);  // rows 7-13
  STORE(0, 7);
  __syncthreads();
  STAGE(21, 1);                          // issue chunk3 load (row 21 only)
#pragma unroll
  for (int rr = 0; rr < 7; ++rr) ROW_BODY(14 + rr, rr, 0); // rows 14-20
  STORE(1, 1);
  __syncthreads();
  ROW_BODY(21, 0, 1);                    // row 21

  // Block reduction -> one plain store per block.
#pragma unroll
  for (int off = 32; off > 0; off >>= 1) tsum += __shfl_down(tsum, off);
  if ((t & 63) == 0) wsum[t >> 6] = tsum;
  __syncthreads();
  if (t == 0) {
    const int bid = blockIdx.x + 2 * (blockIdx.y + 32 * blockIdx.z);
    partials[bid] = wsum[0] + wsum[1] + wsum[2] + wsum[3];
  }
}

__global__ __launch_bounds__(256) void ssim_reduce(
    const float* __restrict__ partials, float* __restrict__ out) {
  __shared__ double wsum[4];
  const int t = threadIdx.x;
  double s = 0.0;
#pragma unroll
  for (int i = 0; i < NBLK / 256; ++i) s += (double)partials[t + 256 * i];
#pragma unroll
  for (int off = 32; off > 0; off >>= 1) s += __shfl_down(s, off);
  if ((t & 63) == 0) wsum[t >> 6] = s;
  __syncthreads();
  if (t == 0)
    out[0] = (float)((wsum[0] + wsum[1] + wsum[2] + wsum[3]) *
                     (1.0 / (double)((size_t)BATCH * IMG_H * IMG_W)));
}

extern "C" void kernel_launch(void* const* d_in, const int* in_sizes, int n_in,
                              void* d_out, int out_size, void* d_ws, size_t ws_size,
                              hipStream_t stream) {
  const float* X = (const float*)d_in[0];
  const float* Y = (const float*)d_in[1];
  const float* K = (const float*)d_in[2];
  float* out = (float*)d_out;
  float* partials = (float*)d_ws;   // NBLK floats, all rewritten every launch

  dim3 grid(IMG_W / TW, IMG_H / TH, BATCH);  // (2, 32, 32) = 2048 blocks
  hipLaunchKernelGGL(ssim_main, grid, dim3(256), 0, stream, X, Y, K, partials);
  hipLaunchKernelGGL(ssim_reduce, dim3(1), dim3(256), 0, stream, partials, out);
}